// Round 10
// baseline (41.872 us; speedup 1.0000x reference)
//
#include <hip/hip_runtime.h>

// Exact decision boundary for  RN_f32(inter/uni) > (float)0.7 :
//   c = 0.7f = 0x3f333333, succ(c) = 0x3f333334 (even mantissa).
//   RN(x) > c  <=>  x >= M  where M = (c + succ(c))/2 (tie rounds to even
//   = succ(c) > c, so ">=" is correct).  M = 23488103 * 2^-25 (25 sig bits),
//   uni has <=24 sig bits  =>  M*(double)uni is EXACT, comparison is exact.
//   uni >= 2 always here (every box area >= 1), so uni==0 never occurs.
#define M_BOUND 0.7000000178813934326171875

__device__ __forceinline__ unsigned long long make_key(unsigned int sbits,
                                                       unsigned int idx) {
    // descending score, ascending index tie-break (stable argsort(-score))
    return (((unsigned long long)(~sbits)) << 32) | idx;
}

// ---------------------------------------------------------------------------
// Kernel 1: original-index-space pair kernel, i-tile SPLIT IN HALF for
// occupancy.  grid = (N/128, N/256) = 2048 blocks -> 8 blocks/CU ->
// 8 waves/SIMD (VGPR 36, LDS 7.5 KB permit it).  Block stages 128 i's;
// wave w owns k in [w*32, w*32+32); lane owns 4 j's (m*64+l).
// Per pair: dir = key_i < key_j (exact order incl. stable tie-break;
// self-pairs vanish).  rank_j += dir; sup_j |= IoU-hit && dir.
// ONE wave-level __any gate per k-iter (4 m-filters OR'd) -> 4x fewer
// branches than per-m gating; exact f64 boundary compare runs rarely.
// Epilogue: LDS-reduce 4 wave partials per j, pack (sup<<16)|rank,
// write part[bih*N + j].
// ---------------------------------------------------------------------------
__global__ __launch_bounds__(256)
void nms_pair(const float4* __restrict__ bbox,
              const float* __restrict__ score,
              unsigned int* __restrict__ part, int N)
{
    __shared__ float4             tile[128];
    __shared__ float              tarea[128];
    __shared__ unsigned long long tkey[128];
    __shared__ unsigned int       red[1024];

    const int bih = blockIdx.x;        // i half-tile (128 i's)
    const int bj  = blockIdx.y;        // j tile (256 j's)
    const int tid = threadIdx.x;
    const int w   = tid >> 6;
    const int l   = tid & 63;

    if (tid < 128) {
        const int i = bih * 128 + tid;
        const float4 bb = bbox[i];
        tile[tid]  = bb;
        tarea[tid] = (bb.z - bb.x) * (bb.w - bb.y);   // single-rounded, as np
        tkey[tid]  = make_key(__float_as_uint(score[i]), (unsigned int)i);
    }

    float4             jb[4];
    float              aj[4];
    unsigned long long jkey[4];
    #pragma unroll
    for (int m = 0; m < 4; ++m) {
        const int j = bj * 256 + m * 64 + l;
        jb[m]   = bbox[j];
        aj[m]   = (jb[m].z - jb[m].x) * (jb[m].w - jb[m].y);
        jkey[m] = make_key(__float_as_uint(score[j]), (unsigned int)j);
    }
    __syncthreads();

    unsigned int c[4]   = {0u, 0u, 0u, 0u};
    unsigned int sup[4] = {0u, 0u, 0u, 0u};
    const int kbase = w * 32;

    #pragma unroll 4
    for (int k = 0; k < 32; ++k) {
        const float4             bo = tile[kbase + k];
        const float              ai = tarea[kbase + k];
        const unsigned long long ik = tkey[kbase + k];

        float inter[4], s[4];
        bool  dir[4];
        bool  anyf = false;
        #pragma unroll
        for (int m = 0; m < 4; ++m) {
            const float iy1 = fmaxf(bo.x, jb[m].x);
            const float ix1 = fmaxf(bo.y, jb[m].y);
            const float iy2 = fminf(bo.z, jb[m].z);
            const float ix2 = fminf(bo.w, jb[m].w);
            const float ih  = fmaxf(iy2 - iy1, 0.0f);
            const float iw  = fmaxf(ix2 - ix1, 0.0f);
            inter[m] = ih * iw;
            s[m]     = ai + aj[m];
            dir[m]   = (ik < jkey[m]);          // i precedes j (exact)
            c[m] += dir[m] ? 1u : 0u;           // rank accumulation
            // cheap conservative filter: exact hit needs inter/s >= M/(1+M)
            // ~= 0.41176; filter fires at >= 0.69/1.69*(1 +- 2^-23)
            // ~= 0.40828 -- margin 0.85% >> rounding, no true hit skipped.
            anyf = anyf | (fmaf(1.69f, inter[m], -0.69f * s[m]) > 0.0f);
        }
        if (__any(anyf)) {                      // one scalar branch per k
            #pragma unroll
            for (int m = 0; m < 4; ++m) {
                float it = inter[m];
                asm volatile("" : "+v"(it));    // block (s - ih*iw) -> fma
                const float uni = s[m] - it;
                const bool hit  = ((double)it >= M_BOUND * (double)uni);
                sup[m] |= (hit && dir[m]) ? 1u : 0u;
            }
        }
    }

    // epilogue: reduce 4 wave-partials per j; pack (sup<<16) | count.
    // per-block c-sum <= 128, block sup-sum <= 4*0x10000: no carry into
    // high16 from counts; across 64 blocks rank-sum <= 8191 < 2^16.
    #pragma unroll
    for (int m = 0; m < 4; ++m)
        red[w * 256 + m * 64 + l] = (sup[m] ? 0x10000u : 0u) + c[m];
    __syncthreads();
    const unsigned int tot = red[tid] + red[256 + tid] +
                             red[512 + tid] + red[768 + tid];
    part[(size_t)bih * N + bj * 256 + tid] = tot;
}

// ---------------------------------------------------------------------------
// Kernel 2: finalize.  tot = sum of 64 half-tile partials per j:
// rank = tot & 0xFFFF, suppressed = (tot >> 16) != 0.  Scatter masked box +
// keep flag to the sorted slot.  d_out: [N*4 floats boxes][N floats keep].
// ---------------------------------------------------------------------------
__global__ __launch_bounds__(256)
void nms_finalize(const float4* __restrict__ bbox,
                  const unsigned int* __restrict__ part,
                  float* __restrict__ out, int N)
{
    const int j = blockIdx.x * 256 + threadIdx.x;
    unsigned int tot = 0;
    #pragma unroll 16
    for (int b = 0; b < 64; ++b)
        tot += part[(size_t)b * N + j];
    const unsigned int r = tot & 0xFFFFu;
    const float s = (tot >> 16) ? 0.0f : 1.0f;
    const float4 bx = bbox[j];
    float4 o;
    o.x = bx.x * s; o.y = bx.y * s; o.z = bx.z * s; o.w = bx.w * s;
    ((float4*)out)[r] = o;
    out[N * 4 + r] = s;
}

extern "C" void kernel_launch(void* const* d_in, const int* in_sizes, int n_in,
                              void* d_out, int out_size, void* d_ws, size_t ws_size,
                              hipStream_t stream) {
    const float* bbox  = (const float*)d_in[0];   // [1, N, 4] (y1,x1,y2,x2)
    const float* score = (const float*)d_in[1];   // [1, N]
    const int N = in_sizes[1];                    // 8192

    unsigned int* part = (unsigned int*)d_ws;     // (N/128) * N * 4 B = 2 MB

    nms_pair<<<dim3(N / 128, N / 256), 256, 0, stream>>>((const float4*)bbox,
                                                         score, part, N);
    nms_finalize<<<N / 256, 256, 0, stream>>>((const float4*)bbox, part,
                                              (float*)d_out, N);
}

// Round 11
// 39.332 us; speedup vs baseline: 1.0646x; 1.0646x over previous
//
#include <hip/hip_runtime.h>

// Exact decision boundary for  RN_f32(inter/uni) > (float)0.7 :
//   c = 0.7f = 0x3f333333, succ(c) = 0x3f333334 (even mantissa).
//   RN(x) > c  <=>  x >= M  where M = (c + succ(c))/2 (tie rounds to even
//   = succ(c) > c, so ">=" is correct).  M = 23488103 * 2^-25 (25 sig bits),
//   uni has <=24 sig bits  =>  M*(double)uni is EXACT, comparison is exact.
//   uni >= 2 always here (every box area >= 1), so uni==0 never occurs.
#define M_BOUND 0.7000000178813934326171875

__device__ __forceinline__ unsigned long long make_key(unsigned int sbits,
                                                       unsigned int idx) {
    // descending score, ascending index tie-break (stable argsort(-score))
    return (((unsigned long long)(~sbits)) << 32) | idx;
}

// ---------------------------------------------------------------------------
// Kernel A: partial rank counts, 2 i-keys per thread, LDS-staged key tile,
// no atomics.  grid = (N/512, N/256) = 512 blocks -> 2 blocks/CU.
// partial[y][i] = #{keys in y-tile < key_i}   (each cell written once)
// ---------------------------------------------------------------------------
__global__ __launch_bounds__(256)
void nms_rank_partial(const float* __restrict__ score,
                      unsigned int* __restrict__ partial, int N)
{
    __shared__ unsigned long long skeys[256];
    const int tid = threadIdx.x;
    const int y   = blockIdx.y;
    const int t   = y * 256 + tid;
    skeys[tid] = make_key(__float_as_uint(score[t]), (unsigned int)t);

    const int i0 = blockIdx.x * 512 + tid;
    const unsigned long long k0 = make_key(__float_as_uint(score[i0      ]), i0      );
    const unsigned long long k1 = make_key(__float_as_uint(score[i0 + 256]), i0 + 256);
    __syncthreads();

    unsigned int c0 = 0, c1 = 0;
    #pragma unroll 16
    for (int k = 0; k < 256; ++k) {
        const unsigned long long ok = skeys[k];
        c0 += (ok < k0) ? 1u : 0u;
        c1 += (ok < k1) ? 1u : 0u;
    }
    unsigned int* row = partial + (size_t)y * N;
    row[i0      ] = c0;
    row[i0 + 256] = c1;
}

// ---------------------------------------------------------------------------
// Kernel B: reduce partial ranks (32 independent coalesced loads), scatter
// box + area to sorted slot, zero the suppression mask.
// ---------------------------------------------------------------------------
__global__ __launch_bounds__(256)
void nms_scatter(const float4* __restrict__ bbox,
                 const unsigned int* __restrict__ partial,
                 float4* __restrict__ sortedBox,
                 float* __restrict__ sortedArea,
                 unsigned int* __restrict__ mask, int N)
{
    const int i = blockIdx.x * 256 + threadIdx.x;
    const int ny = N / 256;
    unsigned int r = 0;
    #pragma unroll 8
    for (int y = 0; y < ny; ++y)
        r += partial[(size_t)y * N + i];
    const float4 b = bbox[i];
    sortedBox[r]  = b;
    sortedArea[r] = (b.z - b.x) * (b.w - b.y);   // (y2-y1)*(x2-x1), once (as np)
    mask[i] = 0u;
}

// ---------------------------------------------------------------------------
// Kernel C: suppressed[j] |= any i<j with IoU > 0.7.  VALU-DIET version:
// per pair = 12 dynamic VALU instrs: 8 (clip chain) + 1 (inter) +
// 1 (t = pai+paj) + 1 (fmaf filter) + 1 (fmax accumulate).  ONE v_cmp +
// scalar branch per k-iter (filter max-reduced over the 4 m's) instead of
// 4 -- 4x less vcc traffic.  Exact f64 boundary compare + diag i<j
// predicate live only in the rarely-taken wave-uniform branch.
// Filter: fires iff 1.69*inter > 0.69*ai + 0.69*aj (each term separately
// rounded) ~ iou > 0.690; true hits need iou > 0.7 -> relative margin
// ~1e-2 >> 5 ulp of accumulated rounding: conservative, no hit skipped.
// 1D triangular grid (bi <= bj); 4 waves split the i-tile; lane owns 4 j's.
// ---------------------------------------------------------------------------
__global__ __launch_bounds__(256)
void nms_suppress(const float4* __restrict__ sortedBox,
                  const float* __restrict__ sortedArea,
                  unsigned int* __restrict__ mask)
{
    // decode triangular index: x = bj*(bj+1)/2 + bi, bi <= bj
    const int x = blockIdx.x;
    int bj = (int)((sqrtf(8.0f * (float)x + 1.0f) - 1.0f) * 0.5f);
    while ((bj + 1) * (bj + 2) / 2 <= x) ++bj;
    while (bj * (bj + 1) / 2 > x) --bj;
    const int bi = x - bj * (bj + 1) / 2;

    __shared__ float4 tile[256];
    __shared__ float  tarea[256];
    const int tid = threadIdx.x;

    tile[tid]  = sortedBox[bi * 256 + tid];
    tarea[tid] = sortedArea[bi * 256 + tid];
    __syncthreads();

    const int w = tid >> 6;           // wave id: k-quarter of the i-tile
    const int l = tid & 63;
    const bool offdiag = (bi < bj);

    float4 jb[4];
    float  aj[4];
    float  paj[4];
    #pragma unroll
    for (int m = 0; m < 4; ++m) {
        const int j = bj * 256 + m * 64 + l;
        jb[m]  = sortedBox[j];
        aj[m]  = sortedArea[j];
        paj[m] = 0.69f * aj[m];
    }

    unsigned int sup[4] = {0u, 0u, 0u, 0u};
    const int kbase = w * 64;
    #pragma unroll 4
    for (int k = 0; k < 64; ++k) {
        const float4 bo  = tile[kbase + k];
        const float  ai  = tarea[kbase + k];
        const float  pai = 0.69f * ai;        // 1 instr per k (1/4 per pair)
        const int    ig  = kbase + k;         // local i index within tile

        float inter[4], f[4];
        #pragma unroll
        for (int m = 0; m < 4; ++m) {
            const float iy1 = fmaxf(bo.x, jb[m].x);
            const float ix1 = fmaxf(bo.y, jb[m].y);
            const float iy2 = fminf(bo.z, jb[m].z);
            const float ix2 = fminf(bo.w, jb[m].w);
            const float ih  = fmaxf(iy2 - iy1, 0.0f);
            const float iw  = fmaxf(ix2 - ix1, 0.0f);
            inter[m] = ih * iw;
            f[m] = fmaf(1.69f, inter[m], -(pai + paj[m]));
        }
        const float anyv = fmaxf(fmaxf(f[0], f[1]), fmaxf(f[2], f[3]));
        if (__any(anyv > 0.0f)) {             // one scalar branch per k-iter
            #pragma unroll
            for (int m = 0; m < 4; ++m) {
                float it = inter[m];
                asm volatile("" : "+v"(it));  // block (s - ih*iw) -> fma
                const float s   = ai + aj[m]; // exact path: single-rounded
                const float uni = s - it;
                const bool hit  = ((double)it >= M_BOUND * (double)uni);
                const bool pred = offdiag || (ig < m * 64 + l);  // i<j on diag
                sup[m] |= (hit && pred) ? 1u : 0u;
            }
        }
    }
    #pragma unroll
    for (int m = 0; m < 4; ++m)
        if (sup[m]) atomicOr(&mask[bj * 256 + m * 64 + l], 1u);
}

// ---------------------------------------------------------------------------
// Kernel D: keep = !suppressed; write masked sorted boxes + keep flags.
// d_out layout: [N*4 floats boxes][N floats keep].
// ---------------------------------------------------------------------------
__global__ __launch_bounds__(256)
void nms_output(const float4* __restrict__ sortedBox,
                const unsigned int* __restrict__ mask,
                float* __restrict__ out, int N)
{
    const int j = blockIdx.x * 256 + threadIdx.x;
    const float s = (mask[j] == 0u) ? 1.0f : 0.0f;
    const float4 b = sortedBox[j];
    float4 o;
    o.x = b.x * s; o.y = b.y * s; o.z = b.z * s; o.w = b.w * s;
    ((float4*)out)[j] = o;
    out[N * 4 + j] = s;
}

extern "C" void kernel_launch(void* const* d_in, const int* in_sizes, int n_in,
                              void* d_out, int out_size, void* d_ws, size_t ws_size,
                              hipStream_t stream) {
    const float* bbox  = (const float*)d_in[0];   // [1, N, 4] (y1,x1,y2,x2)
    const float* score = (const float*)d_in[1];   // [1, N]
    const int N = in_sizes[1];                    // 8192
    const int nb = N / 256;                       // 32

    char* ws = (char*)d_ws;
    float4*       sortedBox  = (float4*)ws;                               // N*16 B
    float*        sortedArea = (float*)(ws + (size_t)N * 16);             // N*4 B
    unsigned int* mask       = (unsigned int*)(ws + (size_t)N * 20);      // N*4 B
    unsigned int* partial    = (unsigned int*)(ws + (size_t)N * 24);      // nb*N*4 B

    nms_rank_partial<<<dim3(N / 512, nb), 256, 0, stream>>>(score, partial, N);
    nms_scatter<<<nb, 256, 0, stream>>>((const float4*)bbox, partial,
                                        sortedBox, sortedArea, mask, N);
    nms_suppress<<<nb * (nb + 1) / 2, 256, 0, stream>>>(sortedBox, sortedArea,
                                                        mask);
    nms_output<<<nb, 256, 0, stream>>>(sortedBox, mask, (float*)d_out, N);
}